// Round 2
// baseline (421.754 us; speedup 1.0000x reference)
//
#include <hip/hip_runtime.h>
#include <hip/hip_fp16.h>
#include <hip/hip_cooperative_groups.h>
#include <math.h>

namespace cg = cooperative_groups;

// ---------------------------------------------------------------------------
// Net_37512244363273: 5-level edge-conditioned graph conv + voxel pooling + FC
// Round 17: mega-fusion. Evidence: per-dispatch ~30-45us floors insensitive to
// internal restructuring (R15->R16 moved only 13us) => cost is dispatch
// turnaround (cache flush + cold re-read + ramp/drain), not per-block work.
// Entire pipeline = ONE cooperative kernel, 15 grid-stride stages separated by
// grid.sync(); 1024 blocks provably co-resident (launch_bounds(256,4), 10.25KB
// LDS). conv0c gets 4-deep load batching (R16 VGPR=36 => 1 load in flight).
// Fallback: same stages as 15 plain dispatches if cooperative launch refused.
// Output: 80 log_softmax + closs = 81 floats.
// ---------------------------------------------------------------------------

#define TILES0 1024                // seg0 tiles (1024 edges each)
#define TSZ0   1024
#define NB0    512                 // seg0 buckets (dst>>7, 128 nodes each)
#define TILES1 256                 // seg1 tiles (1024 edges each)
#define TSZ1   1024
#define NB1    512                 // seg1 buckets (dst>>5, 32 nodes each)

__device__ __forceinline__ float ftanh(float x) {
    float e = __expf(2.f * x);
    return 1.f - 2.f / (e + 1.f);
}

struct SegArgs {
    const int* idx[10];
    int*       cnt[10];
    int*       rp [10];
    int*       out[10];
    int        n  [10];
    int        nb [10];
    int        tstart[11];
};

struct ScanAux {
    int* tilesum;
    int* tileoff;
    int  sstart[11];
    int  T;
};

struct HArgs {
    const float* eattr[5];
    const float* w1[5];
    const float* b1[5];
    float*       H;
    int          E[5];
    int          bstart[6];
};

struct WArgs {
    const float* w2[5];
    const float* b2[5];
    const float* H;
    float*       sq;
    int          cico[5];
    int          E[5];
};

struct MegaArgs {
    SegArgs sa; ScanAux sx; HArgs ha; WArgs wa;
    const int* src0; const int* dst0; const float* ea0;
    const int* src1; const int* dst1; const float* ea1;
    const float* x0; const float* pos0;
    int* M; int* M2; int* colTotal; int* bucketStart;
    int* M1; int* M21; int* ct1; int* bs1;
    float4* pay2; float4* pay1; float4* rec1; int* rp1;
    const float* w1[5]; const float* b1[5]; const float* w2[5]; const float* b2[5];
    const float* root[5]; const float* bias[5];
    const int* rp[5]; const int* eid[5]; const int* srcL[5]; const float* eaL[5];
    const int* crp[5]; const int* cnid[5];
    float* y; float* xn[5]; float* pn[5];
    const float* fc_w; const float* fc_b; float* out;
    int hsB;
    int W[16];                       // stage widths W[1]..W[15]
};

// ---------------------------------------------------------------------------
// shared-pool carved role bodies
// ---------------------------------------------------------------------------

__device__ void scan512(const int* __restrict__ in, int* __restrict__ outExcl,
                        int t, int* sc)
{
    int a0 = in[2 * t], a1 = in[2 * t + 1];
    int ps = a0 + a1;
    sc[t] = ps;
    __syncthreads();
    for (int d = 1; d < 256; d <<= 1) {
        int u = (t >= d) ? sc[t - d] : 0;
        __syncthreads();
        sc[t] += u;
        __syncthreads();
    }
    int excl = sc[t] - ps;
    outExcl[2 * t]     = excl;
    outExcl[2 * t + 1] = excl + a0;
    if (t == 255) outExcl[512] = sc[255];
}

__device__ __forceinline__ void c0_accum(float* nacc, int bin0, float4 R)
{
    union HU { float f; __half2 h2; } a01, a23;
    a01.f = R.y; a23.f = R.z;
    unsigned wbits = __float_as_uint(R.w);
    int node = (int)(wbits >> 16) - bin0;
    float xv = R.x;
    atomicAdd(&nacc[node], xv);
    atomicAdd(&nacc[128 + node], __low2float(a01.h2)  * xv);
    atomicAdd(&nacc[256 + node], __high2float(a01.h2) * xv);
    atomicAdd(&nacc[384 + node], __low2float(a23.h2)  * xv);
    atomicAdd(&nacc[512 + node], __high2float(a23.h2) * xv);
    atomicAdd(&nacc[640 + node],
              __half2float(__ushort_as_half((unsigned short)(wbits & 0xffffu))) * xv);
    atomicAdd(&nacc[768 + node], 1.f);
}

template<int CO>
__device__ void pool_body(int NN, const int* __restrict__ crp,
                          const int* __restrict__ cnid,
                          const float* __restrict__ y, const float* __restrict__ pos,
                          float* __restrict__ xn, float* __restrict__ pn, int gt)
{
    if (gt >= NN * (CO + 3)) return;
    int c = gt / (CO + 3), o = gt % (CO + 3);
    int r0 = crp[c], r1 = crp[c + 1];
    int d = r1 - r0;
    if (o < CO) {
        float m = -INFINITY;
        for (int j = r0; j < r1; j++)
            m = fmaxf(m, y[(size_t)cnid[j] * CO + o]);
        if (d == 0 || !isfinite(m)) m = 0.f;
        xn[c * (CO + 3) + o] = m;
    } else {
        int k = o - CO;
        float sum = 0.f;
        for (int j = r0; j < r1; j++)
            sum += pos[cnid[j] * 3 + k];
        float pm = sum / fmaxf((float)d, 1.f);
        xn[c * (CO + 3) + CO + k] = pm;
        pn[c * 3 + k] = pm;
    }
}

template<int CI, int CO>
__device__ void coop_body(const MegaArgs& A, int l, int v, int t,
                          float* SP, int* iSP)
{
    constexpr int CH = 48, CICO = CI * CO;
    int*   eb  = iSP;            // 48
    int*   svb = iSP + 48;       // 48
    float* w1s = SP + 96;        // 20
    float* hb  = SP + 116;       // 288
    float* Sx  = SP + 404;       // 6*CI <= 234
    float* xs  = SP + 640;       // CH*CI <= 1872
    const int* rp = A.rp[l]; const int* eid = A.eid[l];
    const int* src = A.srcL[l]; const float* eattr = A.eaL[l];
    const float* x = A.xn[l - 1]; float* y = A.y;

    if (t < 20) w1s[t] = (t < 15) ? A.w1[l][t] : A.b1[l][t - 15];
    int r0 = rp[v], r1 = rp[v + 1];
    int d = r1 - r0;
    float acc = 0.f;

    for (int c0 = r0; c0 < r1; c0 += CH) {
        int cn = min(CH, r1 - c0);
        if (t < cn) {
            int e = eid[c0 + t];
            eb[t]  = e;
            svb[t] = src[e];
            hb[t * 6] = 1.f;
        }
        __syncthreads();
        if (t < cn * 5) {
            int j = t / 5, k = t % 5;
            int e = eb[j];
            float e0 = eattr[e * 3], e1 = eattr[e * 3 + 1], e2 = eattr[e * 3 + 2];
            hb[j * 6 + 1 + k] =
                ftanh(e0 * w1s[k] + e1 * w1s[5 + k] + e2 * w1s[10 + k] + w1s[15 + k]);
        }
        for (int u = t; u < cn * CI; u += 256)
            xs[u] = x[(size_t)svb[u / CI] * CI + (u % CI)];
        __syncthreads();
        if (t < 6 * CI) {
            int i = t / 6, k6 = t % 6;
            for (int j = 0; j < cn; j++)
                acc += hb[j * 6 + k6] * xs[j * CI + i];
        }
        __syncthreads();
    }

    if (t < 6 * CI) Sx[t] = acc;
    __syncthreads();

    if (t < CO) {
        float m = 0.f;
        const float* w2 = A.w2[l]; const float* b2 = A.b2[l];
        for (int i = 0; i < CI; i++) {
            m += b2[i * CO + t] * Sx[i * 6];
            #pragma unroll
            for (int k = 0; k < 5; k++)
                m += w2[k * CICO + i * CO + t] * Sx[i * 6 + 1 + k];
        }
        m /= fmaxf((float)d, 1.f);
        for (int i = 0; i < CI; i++)
            m += x[(size_t)v * CI + i] * A.root[l][i * CO + t];
        y[(size_t)v * CO + t] = m + A.bias[l][t];
    }
    __syncthreads();
}

__device__ void conv1s_body(const MegaArgs& A, int v, int t, float* SP, int* iSP)
{
    constexpr int CI = 15, CO = 20, CH = 48, CICO = CI * CO;
    float4* recb = (float4*)SP;          // [0,192) floats
    int*    svb  = iSP + 192;            // 48
    float*  hb   = SP + 240;             // 288
    float*  xs   = SP + 528;             // 720
    float*  Sx   = SP + 1248;            // 90
    float*  w1s  = SP + 1344;            // 20
    const float* x = A.xn[0]; float* y = A.y;

    if (t < 20) w1s[t] = (t < 15) ? A.w1[1][t] : A.b1[1][t - 15];
    int r0 = A.rp1[v], r1 = A.rp1[v + 1];
    int d = r1 - r0;
    float acc = 0.f;

    for (int c0 = r0; c0 < r1; c0 += CH) {
        int cn = min(CH, r1 - c0);
        if (t < cn) {
            float4 R = A.rec1[c0 + t];
            recb[t] = R;
            svb[t]  = (int)(__float_as_uint(R.x) & 0xffffu);
            hb[t * 6] = 1.f;
        }
        __syncthreads();
        if (t < cn * 5) {
            int j = t / 5, k = t % 5;
            float e0 = recb[j].y, e1 = recb[j].z, e2 = recb[j].w;
            hb[j * 6 + 1 + k] =
                ftanh(e0 * w1s[k] + e1 * w1s[5 + k] + e2 * w1s[10 + k] + w1s[15 + k]);
        }
        for (int u = t; u < cn * CI; u += 256)
            xs[u] = x[(size_t)svb[u / CI] * CI + (u % CI)];
        __syncthreads();
        if (t < 6 * CI) {
            int i = t / 6, k6 = t % 6;
            for (int j = 0; j < cn; j++)
                acc += hb[j * 6 + k6] * xs[j * CI + i];
        }
        __syncthreads();
    }

    if (t < 6 * CI) Sx[t] = acc;
    __syncthreads();

    if (t < CO) {
        float m = 0.f;
        const float* w2 = A.w2[1]; const float* b2 = A.b2[1];
        for (int i = 0; i < CI; i++) {
            m += b2[i * CO + t] * Sx[i * 6];
            #pragma unroll
            for (int k = 0; k < 5; k++)
                m += w2[k * CICO + i * CO + t] * Sx[i * 6 + 1 + k];
        }
        m /= fmaxf((float)d, 1.f);
        for (int i = 0; i < CI; i++)
            m += x[(size_t)v * CI + i] * A.root[1][i * CO + t];
        y[(size_t)v * CO + t] = m + A.bias[1][t];
    }
    __syncthreads();
}

// ---------------------------------------------------------------------------
// run_stage: one virtual block of stage s
// ---------------------------------------------------------------------------
__device__ void run_stage(const MegaArgs& A, int s, int vb, int t, float* SP)
{
    int* iSP = (int*)SP;

    switch (s) {
    case 1: {                                      // cnt0 | cnt1 | hstats | hist
        int B = vb;
        if (B < TILES0) {
            int* sh = iSP;
            for (int u = t; u < NB0; u += 256) sh[u] = 0;
            __syncthreads();
            int base = B * TSZ0 + t;
            #pragma unroll
            for (int it = 0; it < 4; it++)
                atomicAdd(&sh[A.dst0[base + it * 256] >> 7], 1);
            __syncthreads();
            for (int u = t; u < NB0; u += 256) A.M[(size_t)B * NB0 + u] = sh[u];
            break;
        }
        B -= TILES0;
        if (B < TILES1) {
            int* sh = iSP;
            for (int u = t; u < NB1; u += 256) sh[u] = 0;
            __syncthreads();
            int base = B * TSZ1 + t;
            #pragma unroll
            for (int it = 0; it < 4; it++)
                atomicAdd(&sh[A.dst1[base + it * 256] >> 5], 1);
            __syncthreads();
            for (int u = t; u < NB1; u += 256) A.M1[(size_t)B * NB1 + u] = sh[u];
            break;
        }
        B -= TILES1;
        if (B < A.hsB) {                           // hstats (levels 1-4)
            const HArgs& ha = A.ha;
            const int K = 8;
            int l = 0;
            while (l < 4 && B >= ha.bstart[l + 1]) l++;
            int bloc = B - ha.bstart[l];
            const float* ea = ha.eattr[l];
            float w1r[15], b1r[5];
            #pragma unroll
            for (int i = 0; i < 15; i++) w1r[i] = ha.w1[l][i];
            #pragma unroll
            for (int i = 0; i < 5; i++)  b1r[i] = ha.b1[l][i];
            float acc[20];
            #pragma unroll
            for (int i = 0; i < 20; i++) acc[i] = 0.f;
            int base = bloc * 256 * K + t;
            for (int it = 0; it < K; it++) {
                int e = base + it * 256;
                if (e < ha.E[l]) {
                    float e0 = ea[e * 3], e1 = ea[e * 3 + 1], e2 = ea[e * 3 + 2];
                    float h[5];
                    #pragma unroll
                    for (int k = 0; k < 5; k++)
                        h[k] = ftanh(e0 * w1r[k] + e1 * w1r[5 + k] + e2 * w1r[10 + k] + b1r[k]);
                    int p = 5;
                    #pragma unroll
                    for (int k = 0; k < 5; k++) {
                        acc[k] += h[k];
                        #pragma unroll
                        for (int k2 = k; k2 < 5; k2++) acc[p++] += h[k] * h[k2];
                    }
                }
            }
            float* red = SP;
            int wid = t >> 6, lane = t & 63;
            #pragma unroll
            for (int v = 0; v < 20; v++) {
                float sv = acc[v];
                #pragma unroll
                for (int o = 32; o; o >>= 1) sv += __shfl_down(sv, o);
                if (lane == 0) red[wid * 20 + v] = sv;
            }
            __syncthreads();
            if (t < 20)
                atomicAdd(&ha.H[l * 20 + t],
                          red[t] + red[20 + t] + red[40 + t] + red[60 + t]);
            break;
        }
        B -= A.hsB;
        {                                          // hist (segs 0-7)
            const SegArgs& a = A.sa;
            int sg = 0;
            while (sg < 9 && B >= a.tstart[sg + 1]) sg++;
            int i0 = (B - a.tstart[sg]) * 1024;
            const int* idx = a.idx[sg];
            int* cnt = a.cnt[sg];
            int n = a.n[sg];
            #pragma unroll
            for (int j = 0; j < 4; j++) {
                int i = i0 + j * 256 + t;
                if (i < n) atomicAdd(&cnt[idx[i]], 1);
            }
        }
        break;
    }

    case 2: {                                      // colscan0 | colscan1 | scanA
        int B = vb;
        int* sc = iSP;
        if (B < NB0) {
            int v[4];
            int s4 = 0;
            #pragma unroll
            for (int j = 0; j < 4; j++) {
                v[j] = A.M[(size_t)(t * 4 + j) * NB0 + B];
                s4 += v[j];
            }
            sc[t] = s4;
            __syncthreads();
            for (int d = 1; d < 256; d <<= 1) {
                int u = (t >= d) ? sc[t - d] : 0;
                __syncthreads();
                sc[t] += u;
                __syncthreads();
            }
            int run = sc[t] - s4;
            #pragma unroll
            for (int j = 0; j < 4; j++) {
                A.M2[(size_t)(t * 4 + j) * NB0 + B] = run;
                run += v[j];
            }
            if (t == 255) A.colTotal[B] = sc[255];
            break;
        }
        B -= NB0;
        if (B < NB1) {
            int v = A.M1[(size_t)t * NB1 + B];
            sc[t] = v;
            __syncthreads();
            for (int d = 1; d < 256; d <<= 1) {
                int u = (t >= d) ? sc[t - d] : 0;
                __syncthreads();
                sc[t] += u;
                __syncthreads();
            }
            A.M21[(size_t)t * NB1 + B] = sc[t] - v;
            if (t == 255) A.ct1[B] = sc[255];
            break;
        }
        {                                          // scanA
            int b = B - NB1;
            const SegArgs& a = A.sa;
            const ScanAux& x = A.sx;
            int sg = 0;
            while (sg < 9 && b >= x.sstart[sg + 1]) sg++;
            int tloc = b - x.sstart[sg];
            int nb = a.nb[sg];
            const int* cnt = a.cnt[sg];
            int i0 = tloc * 4096 + t * 16;
            int sum = 0;
            #pragma unroll
            for (int k = 0; k < 16; k++) {
                int i = i0 + k;
                if (i < nb) sum += cnt[i];
            }
            #pragma unroll
            for (int o = 32; o; o >>= 1) sum += __shfl_down(sum, o);
            if ((t & 63) == 0) sc[t >> 6] = sum;
            __syncthreads();
            if (t == 0)
                x.tilesum[b] = sc[0] + sc[1] + sc[2] + sc[3];
        }
        break;
    }

    case 3: {                                      // bktscan0 | scanB | bktscan1
        if (vb == 0) {
            scan512(A.colTotal, A.bucketStart, t, iSP);
        } else if (vb == 2) {
            scan512(A.ct1, A.bs1, t, iSP);
        } else if (t < 64) {                       // scanB (wave 0)
            const SegArgs& a = A.sa;
            const ScanAux& x = A.sx;
            int lane = t;
            int orig = (lane < x.T) ? x.tilesum[lane] : 0;
            int val = orig;
            #pragma unroll
            for (int d = 1; d < 64; d <<= 1) {
                int v = __shfl_up(val, d);
                if (lane >= d) val += v;
            }
            int excl = val - orig;
            int sg = 0;
            while (sg < 9 && lane >= x.sstart[sg + 1]) sg++;
            int segExcl = __shfl(excl, x.sstart[sg]);
            if (lane < x.T) {
                x.tileoff[lane] = excl - segExcl;
                if (lane == x.sstart[sg + 1] - 1)
                    a.rp[sg][a.nb[sg]] = val - segExcl;
            }
        }
        break;
    }

    case 4: {                                      // part0 | part1 | scanC
        int B = vb;
        if (B < TILES0) {                          // part0
            int* shi = iSP;                        // 512
            float* shf = SP + 512;                 // 100
            int tile = B;
            for (int u = t; u < NB0; u += 256)
                shi[u] = A.bucketStart[u] + A.M2[(size_t)tile * NB0 + u];
            if (t < 15) shf[t] = A.w1[0][t];
            if (t >= 32 && t < 37) shf[15 + t - 32] = A.b1[0][t - 32];
            __syncthreads();

            float acc[20];
            #pragma unroll
            for (int i = 0; i < 20; i++) acc[i] = 0.f;

            int base = tile * TSZ0 + t;
            #pragma unroll
            for (int it = 0; it < 4; it++) {
                int i = base + it * 256;
                int d = A.dst0[i];
                float e0 = A.ea0[i * 3], e1 = A.ea0[i * 3 + 1], e2 = A.ea0[i * 3 + 2];
                float h[5];
                #pragma unroll
                for (int k = 0; k < 5; k++)
                    h[k] = ftanh(e0 * shf[k] + e1 * shf[5 + k] + e2 * shf[10 + k] + shf[15 + k]);
                int p = 5;
                #pragma unroll
                for (int k = 0; k < 5; k++) {
                    acc[k] += h[k];
                    #pragma unroll
                    for (int k2 = k; k2 < 5; k2++) acc[p++] += h[k] * h[k2];
                }
                float xv = A.x0[A.src0[i]];
                union HU { __half2 h2; float f; } p01, p23;
                p01.h2 = __floats2half2_rn(h[0], h[1]);
                p23.h2 = __floats2half2_rn(h[2], h[3]);
                unsigned wbits = ((unsigned)d << 16) |
                                 (unsigned)__half_as_ushort(__float2half_rn(h[4]));
                int ps = atomicAdd(&shi[d >> 7], 1);
                A.pay2[ps] = make_float4(xv, p01.f, p23.f, __uint_as_float(wbits));
            }

            int wid = t >> 6, lane = t & 63;
            #pragma unroll
            for (int v = 0; v < 20; v++) {
                float sv = acc[v];
                #pragma unroll
                for (int o = 32; o; o >>= 1) sv += __shfl_down(sv, o);
                if (lane == 0) shf[20 + wid * 20 + v] = sv;
            }
            __syncthreads();
            if (t < 20)
                atomicAdd(&A.ha.H[t],
                          shf[20 + t] + shf[40 + t] + shf[60 + t] + shf[80 + t]);
            break;
        }
        B -= TILES0;
        if (B < TILES1) {                          // part1
            int* shi = iSP;
            int tile = B;
            for (int u = t; u < NB1; u += 256)
                shi[u] = A.bs1[u] + A.M21[(size_t)tile * NB1 + u];
            __syncthreads();
            int base = tile * TSZ1 + t;
            #pragma unroll
            for (int it = 0; it < 4; it++) {
                int i = base + it * 256;
                int d = A.dst1[i];
                int key = (d << 16) | A.src1[i];
                float e0 = A.ea1[i * 3], e1 = A.ea1[i * 3 + 1], e2 = A.ea1[i * 3 + 2];
                int ps = atomicAdd(&shi[d >> 5], 1);
                A.pay1[ps] = make_float4(__int_as_float(key), e0, e1, e2);
            }
            break;
        }
        {                                          // scanC
            int b = B - TILES1;
            const SegArgs& a = A.sa;
            const ScanAux& x = A.sx;
            int* shi = iSP;
            int sg = 0;
            while (sg < 9 && b >= x.sstart[sg + 1]) sg++;
            int tloc = b - x.sstart[sg];
            int nb = a.nb[sg];
            const int* cnt = a.cnt[sg];
            int* rp = a.rp[sg];
            int i0 = tloc * 4096 + t * 16;
            int v[16];
            int sum = 0;
            #pragma unroll
            for (int k = 0; k < 16; k++) {
                int i = i0 + k;
                v[k] = (i < nb) ? cnt[i] : 0;
                sum += v[k];
            }
            int acc = sum;
            shi[t] = acc;
            __syncthreads();
            for (int d = 1; d < 256; d <<= 1) {
                int t2 = (t >= d) ? shi[t - d] : 0;
                __syncthreads();
                acc += t2;
                shi[t] = acc;
                __syncthreads();
            }
            int running = x.tileoff[b] + (acc - sum);
            #pragma unroll
            for (int k = 0; k < 16; k++) {
                int i = i0 + k;
                if (i < nb) rp[i] = running;
                running += v[k];
            }
        }
        break;
    }

    case 5: {                                      // conv0c | bucket1 | wstats | scatter
        int B = vb;
        if (B < NB0) {                             // conv0c (4-deep batched)
            float* wsm  = SP;                      // 96
            float* nacc = SP + 96;                 // 896
            if (t < 60) wsm[t] = A.w2[0][t];
            else if (t >= 64  && t < 76)  wsm[60 + t - 64]  = A.b2[0][t - 64];
            else if (t >= 128 && t < 140) wsm[72 + t - 128] = A.root[0][t - 128];
            else if (t >= 192 && t < 204) wsm[84 + t - 192] = A.bias[0][t - 192];
            for (int u = t; u < 7 * 128; u += 256) nacc[u] = 0.f;
            __syncthreads();

            int lo = A.bucketStart[B], hi = A.bucketStart[B + 1];
            int bin0 = B << 7;
            for (int j0 = lo + t; j0 < hi; j0 += 1024) {
                float4 R0 = A.pay2[j0];
                float4 R1, R2, R3;
                bool g1 = j0 + 256 < hi, g2 = j0 + 512 < hi, g3 = j0 + 768 < hi;
                if (g1) R1 = A.pay2[j0 + 256];
                if (g2) R2 = A.pay2[j0 + 512];
                if (g3) R3 = A.pay2[j0 + 768];
                c0_accum(nacc, bin0, R0);
                if (g1) c0_accum(nacc, bin0, R1);
                if (g2) c0_accum(nacc, bin0, R2);
                if (g3) c0_accum(nacc, bin0, R3);
            }
            __syncthreads();

            if (t < 128) {
                int v = bin0 + t;
                float deg = nacc[768 + t];
                float S0 = nacc[t],       S1 = nacc[128 + t], S2 = nacc[256 + t];
                float S3 = nacc[384 + t], S4 = nacc[512 + t], S5 = nacc[640 + t];
                float inv = 1.f / fmaxf(deg, 1.f);
                float xv = A.x0[v];
                #pragma unroll
                for (int o = 0; o < 12; o++) {
                    float msg = wsm[60 + o] * S0 + wsm[o] * S1 + wsm[12 + o] * S2 +
                                wsm[24 + o] * S3 + wsm[36 + o] * S4 + wsm[48 + o] * S5;
                    A.y[v * 12 + o] = msg * inv + xv * wsm[72 + o] + wsm[84 + o];
                }
            }
            break;
        }
        B -= NB0;
        if (B < NB1) {                             // bucket1 (2-deep batched)
            int* hist = iSP;                       // 32
            int* cur  = iSP + 32;                  // 32
            int b = B;
            int lo = A.bs1[b], hi = A.bs1[b + 1];
            int bin0 = b << 5;
            if (t < 32) hist[t] = 0;
            __syncthreads();
            const float* payw = (const float*)A.pay1;
            for (int j0 = lo + t; j0 < hi; j0 += 512) {
                unsigned k0 = __float_as_uint(payw[4 * j0]);
                int j1 = j0 + 256;
                bool g1 = j1 < hi;
                unsigned k1 = g1 ? __float_as_uint(payw[4 * j1]) : 0u;
                atomicAdd(&hist[(int)(k0 >> 16) - bin0], 1);
                if (g1) atomicAdd(&hist[(int)(k1 >> 16) - bin0], 1);
            }
            __syncthreads();
            if (t < 32) {
                int v = hist[t];
                int val = v;
                #pragma unroll
                for (int d = 1; d < 32; d <<= 1) {
                    int u = __shfl_up(val, d);
                    if (t >= d) val += u;
                }
                cur[t] = lo + val - v;
                A.rp1[bin0 + t] = lo + val - v;
                if (b == NB1 - 1 && t == 31) A.rp1[NB1 * 32] = hi;
            }
            __syncthreads();
            for (int j0 = lo + t; j0 < hi; j0 += 512) {
                float4 R0 = A.pay1[j0];
                int j1 = j0 + 256;
                bool g1 = j1 < hi;
                float4 R1;
                if (g1) R1 = A.pay1[j1];
                int rel0 = (int)(__float_as_uint(R0.x) >> 16) - bin0;
                int p0 = atomicAdd(&cur[rel0], 1);
                A.rec1[p0] = R0;
                if (g1) {
                    int rel1 = (int)(__float_as_uint(R1.x) >> 16) - bin0;
                    int p1 = atomicAdd(&cur[rel1], 1);
                    A.rec1[p1] = R1;
                }
            }
            break;
        }
        B -= NB1;
        if (B < 5) {                               // wstats (wave 0)
            if (t < 64) {
                const WArgs& wa = A.wa;
                int l = B;
                const float* w2l = wa.w2[l];
                const float* b2l = wa.b2[l];
                int cico = wa.cico[l];
                float d[21];
                #pragma unroll
                for (int i = 0; i < 21; i++) d[i] = 0.f;
                for (int u = t; u < cico; u += 64) {
                    float b = b2l[u];
                    float w[5];
                    #pragma unroll
                    for (int k = 0; k < 5; k++) w[k] = w2l[k * cico + u];
                    int p = 0;
                    #pragma unroll
                    for (int k = 0; k < 5; k++) {
                        #pragma unroll
                        for (int k2 = k; k2 < 5; k2++) d[p++] += w[k] * w[k2];
                    }
                    #pragma unroll
                    for (int k = 0; k < 5; k++) d[15 + k] += b * w[k];
                    d[20] += b * b;
                }
                #pragma unroll
                for (int i = 0; i < 21; i++) {
                    #pragma unroll
                    for (int off = 32; off; off >>= 1) d[i] += __shfl_down(d[i], off);
                }
                if (t == 0) {
                    const float* H1 = wa.H + l * 20;
                    const float* H2 = H1 + 5;
                    float sq = (float)wa.E[l] * d[20];
                    #pragma unroll
                    for (int k = 0; k < 5; k++) sq += 2.f * d[15 + k] * H1[k];
                    int p = 0;
                    #pragma unroll
                    for (int k = 0; k < 5; k++) {
                        #pragma unroll
                        for (int k2 = k; k2 < 5; k2++) {
                            sq += ((k == k2) ? 1.f : 2.f) * d[p] * H2[p];
                            p++;
                        }
                    }
                    wa.sq[l] = sq;
                }
            }
            break;
        }
        B -= 5;
        {                                          // scatter (segs 0-7)
            const SegArgs& a = A.sa;
            int sg = 0;
            while (sg < 9 && B >= a.tstart[sg + 1]) sg++;
            int i0 = (B - a.tstart[sg]) * 1024;
            const int* idx = a.idx[sg];
            int* cnt = a.cnt[sg];
            const int* rp = a.rp[sg];
            int* out = a.out[sg];
            int n = a.n[sg];
            #pragma unroll
            for (int j = 0; j < 4; j++) {
                int i = i0 + j * 256 + t;
                if (i < n) {
                    int d = idx[i];
                    int p = atomicSub(&cnt[d], 1) - 1;
                    out[rp[d] + p] = i;
                }
            }
        }
        break;
    }

    case 6:
        pool_body<12>(16384, A.crp[0], A.cnid[0], A.y, A.pos0,
                      A.xn[0], A.pn[0], vb * 256 + t);
        break;
    case 7:
        conv1s_body(A, vb, t, SP, iSP);
        break;
    case 8:
        pool_body<20>(4096, A.crp[1], A.cnid[1], A.y, A.pn[0],
                      A.xn[1], A.pn[1], vb * 256 + t);
        break;
    case 9:
        coop_body<23, 28>(A, 2, vb, t, SP, iSP);
        break;
    case 10:
        pool_body<28>(1024, A.crp[2], A.cnid[2], A.y, A.pn[1],
                      A.xn[2], A.pn[2], vb * 256 + t);
        break;
    case 11:
        coop_body<31, 36>(A, 3, vb, t, SP, iSP);
        break;
    case 12:
        pool_body<36>(256, A.crp[3], A.cnid[3], A.y, A.pn[2],
                      A.xn[3], A.pn[3], vb * 256 + t);
        break;
    case 13:
        coop_body<39, 44>(A, 4, vb, t, SP, iSP);
        break;
    case 14:
        pool_body<44>(64, A.crp[4], A.cnid[4], A.y, A.pn[3],
                      A.xn[4], A.pn[4], vb * 256 + t);
        break;

    case 15: {                                     // fc (single virtual block)
        float* logit = SP;                         // 80
        float* roff  = SP + 80;                    // 8
        const float* x5 = A.xn[4];
        if (t < 80) {
            int b = t / 10, j = t % 10;
            float acc = A.fc_b[j];
            for (int k = 0; k < 376; k++)
                acc += x5[b * 376 + k] * A.fc_w[k * 10 + j];
            logit[t] = acc;
        }
        __syncthreads();
        if (t < 8) {
            float m = -1e30f;
            for (int j = 0; j < 10; j++) m = fmaxf(m, logit[t * 10 + j]);
            float ssum = 0.f;
            for (int j = 0; j < 10; j++) ssum += expf(logit[t * 10 + j] - m);
            roff[t] = m + logf(ssum);
        }
        __syncthreads();
        if (t < 80) A.out[t] = logit[t] - roff[t / 10];
        if (t == 0) {
            const float* sq = A.wa.sq;
            float closs = 0.f;
            closs += sq[0] * (1.0f / 12582912.0f);
            closs += sq[1] * (1.0f / 78643200.0f);
            closs += sq[2] * (1.0f / 42205184.0f);
            closs += sq[3] * (1.0f / 18284544.0f);
            closs += sq[4] * (1.0f / 7028736.0f);
            A.out[80] = closs;
        }
        break;
    }
    }
}

// ---------------------------------------------------------------------------
// mega kernel (cooperative) + per-stage fallback kernel
// ---------------------------------------------------------------------------
__global__ __launch_bounds__(256, 4) void mega_k(MegaArgs A)
{
    __shared__ alignas(16) float SP[2560];
    cg::grid_group grid = cg::this_grid();
    const int t = threadIdx.x;
    const int G = gridDim.x;

    for (int s = 1; s <= 15; s++) {
        for (int vb = blockIdx.x; vb < A.W[s]; vb += G) {
            run_stage(A, s, vb, t, SP);
            __syncthreads();
        }
        grid.sync();
    }
}

__global__ __launch_bounds__(256, 4) void stage_k(MegaArgs A, int s)
{
    __shared__ alignas(16) float SP[2560];
    run_stage(A, s, blockIdx.x, threadIdx.x, SP);
}

// ---------------------------------------------------------------------------

extern "C" void kernel_launch(void* const* d_in, const int* in_sizes, int n_in,
                              void* d_out, int out_size, void* d_ws, size_t ws_size,
                              hipStream_t stream)
{
    static const int NSa[6] = {65536, 16384, 4096, 1024, 256, 64};
    static const int ESa[5] = {1048576, 262144, 65536, 16384, 4096};
    static const int COa[5] = {12, 20, 28, 36, 44};
    static const int CIa[5] = {1, 15, 23, 31, 39};

    const float* x0   = (const float*)d_in[0];
    const float* pos0 = (const float*)d_in[1];

    // ---- workspace layout (words) ----
    int* wsw = (int*)d_ws;
    size_t off = 0;
    auto alw = [&](size_t n) -> size_t {
        size_t p = off; off += (n + 63) & ~(size_t)63; return p;
    };
    size_t degO[5], cdegO[5];
    for (int l = 2; l < 5; l++) degO[l]  = alw(NSa[l]);
    for (int l = 0; l < 5; l++) cdegO[l] = alw(NSa[l + 1]);
    size_t HO = alw(100);
    size_t zeroWords = off;                               // zero-init to here
    size_t rpO[5], crpO[5], eidO[5], cnidO[5];
    rpO[1] = alw(NSa[1] + 1);                             // rp1 (written by bucket1)
    for (int l = 2; l < 5; l++) rpO[l]  = alw(NSa[l] + 1);
    for (int l = 0; l < 5; l++) crpO[l] = alw(NSa[l + 1] + 1);
    for (int l = 2; l < 5; l++) eidO[l] = alw(ESa[l]);
    for (int l = 0; l < 5; l++) cnidO[l] = alw(NSa[l]);
    size_t tsO  = alw(64);
    size_t toO  = alw(64);
    size_t MO   = alw((size_t)TILES0 * NB0);
    size_t M2O  = alw((size_t)TILES0 * NB0);
    size_t ctO  = alw(NB0);
    size_t bsO  = alw(NB0 + 1);
    size_t payO = alw((size_t)ESa[0] * 4);                // seg0 16B records
    size_t M1O  = alw((size_t)TILES1 * NB1);
    size_t M21O = alw((size_t)TILES1 * NB1);
    size_t ct1O = alw(NB1);
    size_t bs1O = alw(NB1 + 1);
    size_t pay1O = alw((size_t)ESa[1] * 4);               // seg1 16B records
    size_t rec1O = alw((size_t)ESa[1] * 4);               // seg1 sorted records
    size_t yO   = alw((size_t)65536 * 12);
    size_t sqO  = alw(8);
    size_t xnO[5], pnO[5];
    for (int l = 0; l < 5; l++) xnO[l] = alw((size_t)NSa[l + 1] * (COa[l] + 3));
    for (int l = 0; l < 5; l++) pnO[l] = alw((size_t)NSa[l + 1] * 3);

    // ---- segs descriptor (edge segs 2-4 + cluster segs 0-4) ----
    SegArgs sa{};
    int nseg = 0;
    for (int l = 2; l < 5; l++) {
        sa.idx[nseg] = (const int*)d_in[3 + 10 * l];
        sa.cnt[nseg] = wsw + degO[l];
        sa.rp [nseg] = wsw + rpO[l];
        sa.out[nseg] = wsw + eidO[l];
        sa.n  [nseg] = ESa[l];
        sa.nb [nseg] = NSa[l];
        nseg++;
    }
    for (int l = 0; l < 5; l++) {
        sa.idx[nseg] = (const int*)d_in[5 + 10 * l];
        sa.cnt[nseg] = wsw + cdegO[l];
        sa.rp [nseg] = wsw + crpO[l];
        sa.out[nseg] = wsw + cnidO[l];
        sa.n  [nseg] = NSa[l];
        sa.nb [nseg] = NSa[l + 1];
        nseg++;
    }
    ScanAux sx{};
    int tiles = 0, btiles = 0;
    for (int s = 0; s < nseg; s++) {
        sa.tstart[s] = tiles;
        tiles += (sa.n[s] + 1023) / 1024;
        sx.sstart[s] = btiles;
        btiles += (sa.nb[s] + 4095) / 4096;
    }
    for (int s = nseg; s <= 10; s++) {
        sa.tstart[s] = tiles;
        sx.sstart[s] = btiles;
        if (s < 10) {
            sa.idx[s] = sa.idx[nseg - 1]; sa.cnt[s] = sa.cnt[nseg - 1];
            sa.rp[s] = sa.rp[nseg - 1];   sa.out[s] = sa.out[nseg - 1];
            sa.n[s] = 0; sa.nb[s] = 8;
        }
    }
    sx.T = btiles;
    sx.tilesum = wsw + tsO;
    sx.tileoff = wsw + toO;

    float*  Hp = (float*)(wsw + HO);

    HArgs ha{};
    int hsB = 0;
    ha.bstart[0] = 0;
    ha.eattr[0] = (const float*)d_in[4];
    ha.w1[0] = (const float*)d_in[6];
    ha.b1[0] = (const float*)d_in[7];
    ha.E[0] = 0;
    for (int l = 1; l < 5; l++) {
        ha.eattr[l] = (const float*)d_in[4 + 10 * l];
        ha.w1[l]    = (const float*)d_in[6 + 10 * l];
        ha.b1[l]    = (const float*)d_in[7 + 10 * l];
        ha.E[l]     = ESa[l];
        ha.bstart[l] = hsB;
        hsB += (ESa[l] + 2047) / 2048;
    }
    ha.bstart[5] = hsB;
    ha.H = Hp;

    WArgs wa{};
    for (int l = 0; l < 5; l++) {
        wa.w2[l]   = (const float*)d_in[8 + 10 * l];
        wa.b2[l]   = (const float*)d_in[9 + 10 * l];
        wa.cico[l] = CIa[l] * COa[l];
        wa.E[l]    = ESa[l];
    }
    wa.H  = Hp;
    wa.sq = (float*)(wsw + sqO);

    // ---- MegaArgs ----
    MegaArgs A{};
    A.sa = sa; A.sx = sx; A.ha = ha; A.wa = wa;
    A.src0 = (const int*)d_in[2];  A.dst0 = (const int*)d_in[3];
    A.ea0  = (const float*)d_in[4];
    A.src1 = (const int*)d_in[12]; A.dst1 = (const int*)d_in[13];
    A.ea1  = (const float*)d_in[14];
    A.x0 = x0; A.pos0 = pos0;
    A.M = wsw + MO; A.M2 = wsw + M2O; A.colTotal = wsw + ctO;
    A.bucketStart = wsw + bsO;
    A.M1 = wsw + M1O; A.M21 = wsw + M21O; A.ct1 = wsw + ct1O; A.bs1 = wsw + bs1O;
    A.pay2 = (float4*)(wsw + payO);
    A.pay1 = (float4*)(wsw + pay1O);
    A.rec1 = (float4*)(wsw + rec1O);
    A.rp1  = wsw + rpO[1];
    for (int l = 0; l < 5; l++) {
        A.w1[l]   = (const float*)d_in[6 + 10 * l];
        A.b1[l]   = (const float*)d_in[7 + 10 * l];
        A.w2[l]   = (const float*)d_in[8 + 10 * l];
        A.b2[l]   = (const float*)d_in[9 + 10 * l];
        A.root[l] = (const float*)d_in[10 + 10 * l];
        A.bias[l] = (const float*)d_in[11 + 10 * l];
        A.srcL[l] = (const int*)d_in[2 + 10 * l];
        A.eaL[l]  = (const float*)d_in[4 + 10 * l];
        A.crp[l]  = wsw + crpO[l];
        A.cnid[l] = wsw + cnidO[l];
        A.xn[l]   = (float*)(wsw + xnO[l]);
        A.pn[l]   = (float*)(wsw + pnO[l]);
    }
    for (int l = 2; l < 5; l++) {
        A.rp[l]  = wsw + rpO[l];
        A.eid[l] = wsw + eidO[l];
    }
    A.y = (float*)(wsw + yO);
    A.fc_w = (const float*)d_in[52];
    A.fc_b = (const float*)d_in[53];
    A.out = (float*)d_out;
    A.hsB = hsB;

    A.W[1]  = TILES0 + TILES1 + hsB + tiles;    // 1620
    A.W[2]  = NB0 + NB1 + btiles;               // 1035
    A.W[3]  = 3;
    A.W[4]  = TILES0 + TILES1 + btiles;         // 1291
    A.W[5]  = NB0 + NB1 + 5 + tiles;            // 1199
    A.W[6]  = (NSa[1] * 15 + 255) / 256;        // 960
    A.W[7]  = NSa[1];                           // 16384
    A.W[8]  = (NSa[2] * 23 + 255) / 256;        // 368
    A.W[9]  = NSa[2];                           // 4096
    A.W[10] = (NSa[3] * 31 + 255) / 256;        // 124
    A.W[11] = NSa[3];                           // 1024
    A.W[12] = (NSa[4] * 39 + 255) / 256;        // 39
    A.W[13] = NSa[4];                           // 256
    A.W[14] = (NSa[5] * 47 + 255) / 256;        // 12
    A.W[15] = 1;

    hipMemsetAsync(d_ws, 0, zeroWords * 4, stream);

    // 1024 blocks provably co-resident: launch_bounds(256,4) => VGPR<=128
    // (4 waves/EU), LDS 10.25KB => 4 blocks/CU x 256 CUs.
    static int coopOK = -1;
    hipError_t err = hipErrorUnknown;
    if (coopOK != 0) {
        void* kargs[] = { (void*)&A };
        err = hipLaunchCooperativeKernel((const void*)mega_k, dim3(1024), dim3(256),
                                         kargs, 0, stream);
        if (coopOK < 0) coopOK = (err == hipSuccess) ? 1 : 0;
    }
    if (coopOK == 0) {
        for (int s = 1; s <= 15; s++)
            stage_k<<<dim3(A.W[s]), dim3(256), 0, stream>>>(A, s);
    }
}